// Round 1
// baseline (981.773 us; speedup 1.0000x reference)
//
#include <hip/hip_runtime.h>
#include <hip/hip_bf16.h>

#define NN 8192      // nodes
#define NE 32768     // edges
#define FD 16        // features
#define DIM 64
#define BT 4
#define RANK 512

// ---------------------------------------------------------------- init: s = relu(x @ W0.T + b0)
__global__ __launch_bounds__(256) void k_init(const float* __restrict__ x,
                                              const float* __restrict__ W0,
                                              const float* __restrict__ b0,
                                              float* __restrict__ s) {
    int gid = blockIdx.x * 256 + threadIdx.x;       // gid = n*64 + d
    int n = gid >> 6, d = gid & 63;
    float acc = b0[d];
    const float* xr = x + n * FD;
    const float* wr = W0 + d * FD;
#pragma unroll
    for (int i = 0; i < FD; ++i) acc += xr[i] * wr[i];
    s[gid] = fmaxf(acc, 0.f);
}

// ---------------------------------------------------------------- degree count
__global__ __launch_bounds__(256) void k_deg(const int* __restrict__ ei, float* __restrict__ deg) {
    int e = blockIdx.x * 256 + threadIdx.x;
    atomicAdd(&deg[ei[NE + e]], 1.0f);
}

__global__ __launch_bounds__(256) void k_invdeg(float* __restrict__ deg) {
    int n = blockIdx.x * 256 + threadIdx.x;
    deg[n] = 1.0f / fmaxf(deg[n], 1.0f);
}

// ---------------------------------------------------------------- per-edge hidden (E,32) + bond argmax
__global__ __launch_bounds__(256) void k_h32bond(const float* __restrict__ ea,
                                                 const float* __restrict__ nnW1,
                                                 const float* __restrict__ nnb1,
                                                 float* __restrict__ h32,
                                                 int* __restrict__ bond) {
    int tid = threadIdx.x;
    int e = blockIdx.x * 8 + (tid >> 5);
    int k = tid & 31;
    float a0 = ea[e * 4 + 0], a1 = ea[e * 4 + 1], a2 = ea[e * 4 + 2], a3 = ea[e * 4 + 3];
    float h = nnb1[k] + a0 * nnW1[k * 4 + 0] + a1 * nnW1[k * 4 + 1]
                      + a2 * nnW1[k * 4 + 2] + a3 * nnW1[k * 4 + 3];
    h32[e * 32 + k] = fmaxf(h, 0.f);
    if (k == 0) {
        int bi = 0; float bv = a0;
        if (a1 > bv) { bv = a1; bi = 1; }
        if (a2 > bv) { bv = a2; bi = 2; }
        if (a3 > bv) { bv = a3; bi = 3; }
        bond[e] = bi;
    }
}

// ---------------------------------------------------------------- M[b] = V[b] @ U[b]   (4 x 64x64)
__global__ __launch_bounds__(256) void k_M(const float* __restrict__ U,
                                           const float* __restrict__ V,
                                           float* __restrict__ M) {
    int b = blockIdx.x;
    for (int idx = threadIdx.x; idx < DIM * DIM; idx += 256) {
        int d = idx >> 6, dp = idx & 63;
        const float* Vp = V + (size_t)b * DIM * RANK + (size_t)d * RANK;
        const float* Up = U + (size_t)b * RANK * DIM + dp;
        float acc = 0.f;
        for (int r = 0; r < RANK; ++r) acc += Vp[r] * Up[(size_t)r * DIM];
        M[b * DIM * DIM + idx] = acc;
    }
}

// ---------------------------------------------------------------- A[n][o*32+k] = sum_i s[n][i]*W2[i*2048 + o*32 + k]
// plain tiled fp32 GEMM: [8192,64] @ [64,2048]
__global__ __launch_bounds__(256) void k_gemm_A(const float* __restrict__ s,
                                                const float* __restrict__ W2,
                                                float* __restrict__ A) {
    __shared__ float St[64][65];
    __shared__ float Bt[64][65];
    int n0 = blockIdx.x * 64;
    int j0 = blockIdx.y * 64;
    int tid = threadIdx.x;
    for (int idx = tid; idx < 4096; idx += 256) {
        int r = idx >> 6, i = idx & 63;
        St[r][i] = s[(size_t)(n0 + r) * DIM + i];
    }
    for (int idx = tid; idx < 4096; idx += 256) {
        int i = idx >> 6, j = idx & 63;
        Bt[i][j] = W2[(size_t)i * 2048 + j0 + j];
    }
    __syncthreads();
    int tx = tid & 15, ty = tid >> 4;
    float acc[4][4] = {};
    for (int i = 0; i < 64; ++i) {
        float bv[4];
#pragma unroll
        for (int q = 0; q < 4; ++q) bv[q] = Bt[i][tx * 4 + q];
#pragma unroll
        for (int a = 0; a < 4; ++a) {
            float sa = St[ty * 4 + a][i];
#pragma unroll
            for (int q = 0; q < 4; ++q) acc[a][q] += sa * bv[q];
        }
    }
    for (int a = 0; a < 4; ++a)
        for (int q = 0; q < 4; ++q)
            A[(size_t)(n0 + ty * 4 + a) * 2048 + j0 + tx * 4 + q] = acc[a][q];
}

// ---------------------------------------------------------------- c[n][o] = sum_i s[n][i]*b2[i*64+o]
__global__ __launch_bounds__(256) void k_c(const float* __restrict__ s,
                                           const float* __restrict__ b2,
                                           float* __restrict__ c) {
    __shared__ float ss[4][64];
    int tid = threadIdx.x, w = tid >> 6, lane = tid & 63;
    int node = blockIdx.x * 4 + w;
    ss[w][lane] = s[(size_t)node * DIM + lane];
    __syncthreads();
    float acc = 0.f;
    for (int i = 0; i < 64; ++i) acc += ss[w][i] * b2[i * 64 + lane];
    c[(size_t)node * DIM + lane] = acc;
}

// ---------------------------------------------------------------- edge message + scatter (A path)
__global__ __launch_bounds__(256) void k_edge(const int* __restrict__ ei,
                                              const float* __restrict__ h32,
                                              const float* __restrict__ A,
                                              const float* __restrict__ c,
                                              float* __restrict__ agg) {
    __shared__ float sh[4][32];
    int tid = threadIdx.x, w = tid >> 6, lane = tid & 63;
    int e = blockIdx.x * 4 + w;
    int src = ei[e], dst = ei[NE + e];
    if (lane < 32) sh[w][lane] = h32[(size_t)e * 32 + lane];
    __syncthreads();
    float acc = c[(size_t)src * DIM + lane];
    const float4* Ap = reinterpret_cast<const float4*>(A + (size_t)src * 2048 + lane * 32);
#pragma unroll
    for (int k8 = 0; k8 < 8; ++k8) {
        float4 a = Ap[k8];
        acc += sh[w][k8 * 4 + 0] * a.x + sh[w][k8 * 4 + 1] * a.y
             + sh[w][k8 * 4 + 2] * a.z + sh[w][k8 * 4 + 3] * a.w;
    }
    atomicAdd(&agg[(size_t)dst * DIM + lane], acc);
}

// ---------------------------------------------------------------- fallback edge message (no A buffer)
__global__ __launch_bounds__(256) void k_edge_direct(const int* __restrict__ ei,
                                                     const float* __restrict__ h32,
                                                     const float* __restrict__ s,
                                                     const float* __restrict__ W2,
                                                     const float* __restrict__ b2,
                                                     float* __restrict__ agg) {
    __shared__ float sh[4][32];
    __shared__ float ss[4][64];
    int tid = threadIdx.x, w = tid >> 6, lane = tid & 63;
    int e = blockIdx.x * 4 + w;
    int src = ei[e], dst = ei[NE + e];
    if (lane < 32) sh[w][lane] = h32[(size_t)e * 32 + lane];
    ss[w][lane] = s[(size_t)src * DIM + lane];
    __syncthreads();
    float acc = 0.f;
    for (int i = 0; i < 64; ++i) {
        const float4* Wp = reinterpret_cast<const float4*>(W2 + (size_t)i * 2048 + lane * 32);
        float mi = b2[i * 64 + lane];
#pragma unroll
        for (int k8 = 0; k8 < 8; ++k8) {
            float4 ww = Wp[k8];
            mi += sh[w][k8 * 4 + 0] * ww.x + sh[w][k8 * 4 + 1] * ww.y
                + sh[w][k8 * 4 + 2] * ww.z + sh[w][k8 * 4 + 3] * ww.w;
        }
        acc += ss[w][i] * mi;
    }
    atomicAdd(&agg[(size_t)dst * DIM + lane], acc);
}

// ---------------------------------------------------------------- node update: NNConv combine + GRU cell
__global__ __launch_bounds__(256) void k_update(float* __restrict__ s,
                                                const float* __restrict__ agg,
                                                const float* __restrict__ inv_deg,
                                                const float* __restrict__ root,
                                                const float* __restrict__ conv_b,
                                                const float* __restrict__ Wih,
                                                const float* __restrict__ Whh,
                                                const float* __restrict__ bih,
                                                const float* __restrict__ bhh) {
    __shared__ float sm_s[4][64];
    __shared__ float sm_m[4][64];
    int tid = threadIdx.x, w = tid >> 6, lane = tid & 63;
    int node = blockIdx.x * 4 + w;
    float hv = s[(size_t)node * DIM + lane];
    sm_s[w][lane] = hv;
    float av = agg[(size_t)node * DIM + lane] * inv_deg[node];
    __syncthreads();
    float m = av + conv_b[lane];
    for (int i = 0; i < 64; ++i) m += sm_s[w][i] * root[i * 64 + lane];
    m = fmaxf(m, 0.f);
    sm_m[w][lane] = m;
    __syncthreads();
    float gr = bih[lane], gz = bih[64 + lane], gn = bih[128 + lane];
    float hr = bhh[lane], hz = bhh[64 + lane], hn = bhh[128 + lane];
    for (int i = 0; i < 64; ++i) {
        float mi = sm_m[w][i], hi = sm_s[w][i];
        gr += mi * Wih[lane * 64 + i];
        gz += mi * Wih[(64 + lane) * 64 + i];
        gn += mi * Wih[(128 + lane) * 64 + i];
        hr += hi * Whh[lane * 64 + i];
        hz += hi * Whh[(64 + lane) * 64 + i];
        hn += hi * Whh[(128 + lane) * 64 + i];
    }
    float r = 1.f / (1.f + expf(-(gr + hr)));
    float z = 1.f / (1.f + expf(-(gz + hz)));
    float nnv = tanhf(gn + r * hn);
    s[(size_t)node * DIM + lane] = (1.f - z) * nnv + z * hv;
}

// ---------------------------------------------------------------- out_edges + out_combine
__global__ __launch_bounds__(256) void k_edges_out(const float* __restrict__ s,
                                                   const float* __restrict__ x,
                                                   const float* __restrict__ W1l,
                                                   const float* __restrict__ b1l,
                                                   const float* __restrict__ WUp,
                                                   const float* __restrict__ bUp,
                                                   float* __restrict__ oe,
                                                   float* __restrict__ oc) {
    __shared__ float sm_s[4][64];
    __shared__ float sm_oe[4][4];
    int tid = threadIdx.x, w = tid >> 6, lane = tid & 63;
    int node = blockIdx.x * 4 + w;
    float sv = s[(size_t)node * DIM + lane];
    sm_s[w][lane] = sv;
    __syncthreads();
    if (lane < 4) {
        float acc = b1l[lane];
        for (int i = 0; i < 64; ++i) acc += sm_s[w][i] * W1l[lane * 64 + i];
        acc = fmaxf(acc, 0.f);
        sm_oe[w][lane] = acc;
        oe[(size_t)node * 4 + lane] = acc;
    }
    __syncthreads();
    float ocv;
    if (x[(size_t)node * FD] == 2.0f) {
        ocv = bUp[lane];
#pragma unroll
        for (int t = 0; t < 4; ++t) ocv += sm_oe[w][t] * WUp[lane * 4 + t];
    } else {
        ocv = sv;
    }
    oc[(size_t)node * DIM + lane] = ocv;
}

// ---------------------------------------------------------------- FGNet edge: me = oc[src] @ M[bond], scatter
__global__ __launch_bounds__(256) void k_fgedge(const int* __restrict__ ei,
                                                const int* __restrict__ bond,
                                                const float* __restrict__ oc,
                                                const float* __restrict__ M,
                                                float* __restrict__ fg_agg) {
    __shared__ float so[4][64];
    int tid = threadIdx.x, w = tid >> 6, lane = tid & 63;
    int e = blockIdx.x * 4 + w;
    int src = ei[e], dst = ei[NE + e];
    int b = bond[e];
    so[w][lane] = oc[(size_t)src * DIM + lane];
    __syncthreads();
    float acc = 0.f;
    const float* Mp = M + b * DIM * DIM;
    for (int d = 0; d < 64; ++d) acc += so[w][d] * Mp[d * 64 + lane];
    atomicAdd(&fg_agg[(size_t)dst * DIM + lane], acc);
}

// ---------------------------------------------------------------- final: msg_f -> msg_to_edge -> out_edges -> log_softmax
__global__ __launch_bounds__(256) void k_final(const float* __restrict__ fg_agg,
                                               const float* __restrict__ inv_deg,
                                               const float* __restrict__ oe,
                                               const float* __restrict__ WDown,
                                               const float* __restrict__ bDown,
                                               const float* __restrict__ weight_e,
                                               const float* __restrict__ linWe,
                                               const float* __restrict__ linbe,
                                               float* __restrict__ out) {
    int tid = threadIdx.x, w = tid >> 6, lane = tid & 63;
    int node = blockIdx.x * 4 + w;
    float mf = fmaxf(fg_agg[(size_t)node * DIM + lane] * inv_deg[node], 0.f);
    float mte[4];
#pragma unroll
    for (int t = 0; t < 4; ++t) {
        float p = mf * WDown[t * 64 + lane];
#pragma unroll
        for (int off = 32; off; off >>= 1) p += __shfl_xor(p, off);
        mte[t] = p + bDown[t];
    }
    float val[4];
    float mx = -1e30f;
#pragma unroll
    for (int t = 0; t < 4; ++t) {
        float acc = linbe[t];
#pragma unroll
        for (int t2 = 0; t2 < 4; ++t2) acc += weight_e[t2] * mte[t2] * linWe[t * 4 + t2];
        val[t] = oe[(size_t)node * 4 + t] + fmaxf(acc, 0.f);
        mx = fmaxf(mx, val[t]);
    }
    float lse = 0.f;
#pragma unroll
    for (int t = 0; t < 4; ++t) lse += expf(val[t] - mx);
    lse = logf(lse);
    if (lane < 4) out[(size_t)node * 4 + lane] = val[lane] - mx - lse;
}

// ================================================================ host
extern "C" void kernel_launch(void* const* d_in, const int* in_sizes, int n_in,
                              void* d_out, int out_size, void* d_ws, size_t ws_size,
                              hipStream_t stream) {
    const float* x       = (const float*)d_in[0];
    const int*   ei      = (const int*)  d_in[1];
    const float* ea      = (const float*)d_in[2];
    const float* W0      = (const float*)d_in[3];
    const float* b0      = (const float*)d_in[4];
    const float* nnW1    = (const float*)d_in[5];
    const float* nnb1    = (const float*)d_in[6];
    const float* nnW2    = (const float*)d_in[7];
    const float* nnb2    = (const float*)d_in[8];
    const float* root    = (const float*)d_in[9];
    const float* conv_b  = (const float*)d_in[10];
    const float* Wih     = (const float*)d_in[11];
    const float* Whh     = (const float*)d_in[12];
    const float* bih     = (const float*)d_in[13];
    const float* bhh     = (const float*)d_in[14];
    const float* W1l     = (const float*)d_in[15];
    const float* b1l     = (const float*)d_in[16];
    const float* WUp     = (const float*)d_in[17];
    const float* bUp     = (const float*)d_in[18];
    const float* WDown   = (const float*)d_in[19];
    const float* bDown   = (const float*)d_in[20];
    const float* U       = (const float*)d_in[21];
    const float* V       = (const float*)d_in[22];
    // d_in[23] weight, d_in[24] linW, d_in[25] linb: dead code (out never reaches output)
    const float* weight_e= (const float*)d_in[26];
    const float* linWe   = (const float*)d_in[27];
    const float* linbe   = (const float*)d_in[28];
    float* out = (float*)d_out;

    char* ws = (char*)d_ws;
    size_t off = 0;
    auto alloc = [&](size_t bytes) { size_t o = off; off = (off + bytes + 255) & ~(size_t)255; return o; };
    float* s      = (float*)(ws + alloc((size_t)NN * DIM * 4));
    float* agg    = (float*)(ws + alloc((size_t)NN * DIM * 4));
    float* h32    = (float*)(ws + alloc((size_t)NE * 32 * 4));
    int*   bond   = (int*)  (ws + alloc((size_t)NE * 4));
    float* deg    = (float*)(ws + alloc((size_t)NN * 4));
    float* oe     = (float*)(ws + alloc((size_t)NN * 4 * 4));
    float* oc     = (float*)(ws + alloc((size_t)NN * DIM * 4));
    float* fg_agg = (float*)(ws + alloc((size_t)NN * DIM * 4));
    float* Mbuf   = (float*)(ws + alloc((size_t)BT * DIM * DIM * 4));
    size_t off_fallback = off;
    float* cbuf   = (float*)(ws + alloc((size_t)NN * DIM * 4));
    float* Abuf   = (float*)(ws + alloc((size_t)NN * 2048 * 4));
    bool useA = ws_size >= off;
    (void)off_fallback; (void)n_in; (void)in_sizes; (void)out_size;

    k_init<<<NN * DIM / 256, 256, 0, stream>>>(x, W0, b0, s);
    hipMemsetAsync(deg, 0, (size_t)NN * 4, stream);
    k_deg<<<NE / 256, 256, 0, stream>>>(ei, deg);
    k_h32bond<<<NE / 8, 256, 0, stream>>>(ea, nnW1, nnb1, h32, bond);
    k_invdeg<<<NN / 256, 256, 0, stream>>>(deg);   // deg now holds 1/clip(deg,1)
    k_M<<<BT, 256, 0, stream>>>(U, V, Mbuf);

    for (int it = 0; it < 3; ++it) {
        hipMemsetAsync(agg, 0, (size_t)NN * DIM * 4, stream);
        if (useA) {
            k_gemm_A<<<dim3(NN / 64, 2048 / 64), 256, 0, stream>>>(s, nnW2, Abuf);
            k_c<<<NN / 4, 256, 0, stream>>>(s, nnb2, cbuf);
            k_edge<<<NE / 4, 256, 0, stream>>>(ei, h32, Abuf, cbuf, agg);
        } else {
            k_edge_direct<<<NE / 4, 256, 0, stream>>>(ei, h32, s, nnW2, nnb2, agg);
        }
        k_update<<<NN / 4, 256, 0, stream>>>(s, agg, deg, root, conv_b, Wih, Whh, bih, bhh);
    }

    k_edges_out<<<NN / 4, 256, 0, stream>>>(s, x, W1l, b1l, WUp, bUp, oe, oc);
    hipMemsetAsync(fg_agg, 0, (size_t)NN * DIM * 4, stream);
    k_fgedge<<<NE / 4, 256, 0, stream>>>(ei, bond, oc, Mbuf, fg_agg);
    k_final<<<NN / 4, 256, 0, stream>>>(fg_agg, deg, oe, WDown, bDown, weight_e, linWe, linbe, out);
}

// Round 2
// 419.466 us; speedup vs baseline: 2.3405x; 2.3405x over previous
//
#include <hip/hip_runtime.h>
#include <hip/hip_bf16.h>

#define NN 8192      // nodes
#define NE 32768     // edges
#define FD 16        // features
#define DIM 64
#define BT 4
#define RANK 512

// ---------------------------------------------------------------- init: s = relu(x @ W0.T + b0)
__global__ __launch_bounds__(256) void k_init(const float* __restrict__ x,
                                              const float* __restrict__ W0,
                                              const float* __restrict__ b0,
                                              float* __restrict__ s) {
    int gid = blockIdx.x * 256 + threadIdx.x;       // gid = n*64 + d
    int n = gid >> 6, d = gid & 63;
    float acc = b0[d];
    const float* xr = x + n * FD;
    const float* wr = W0 + d * FD;
#pragma unroll
    for (int i = 0; i < FD; ++i) acc += xr[i] * wr[i];
    s[gid] = fmaxf(acc, 0.f);
}

// ---------------------------------------------------------------- degree count
__global__ __launch_bounds__(256) void k_deg(const int* __restrict__ ei, float* __restrict__ deg) {
    int e = blockIdx.x * 256 + threadIdx.x;
    atomicAdd(&deg[ei[NE + e]], 1.0f);
}

__global__ __launch_bounds__(256) void k_invdeg(float* __restrict__ deg) {
    int n = blockIdx.x * 256 + threadIdx.x;
    deg[n] = 1.0f / fmaxf(deg[n], 1.0f);
}

// ---------------------------------------------------------------- per-edge hidden (E,32) + bond argmax
__global__ __launch_bounds__(256) void k_h32bond(const float* __restrict__ ea,
                                                 const float* __restrict__ nnW1,
                                                 const float* __restrict__ nnb1,
                                                 float* __restrict__ h32,
                                                 int* __restrict__ bond) {
    int tid = threadIdx.x;
    int e = blockIdx.x * 8 + (tid >> 5);
    int k = tid & 31;
    float a0 = ea[e * 4 + 0], a1 = ea[e * 4 + 1], a2 = ea[e * 4 + 2], a3 = ea[e * 4 + 3];
    float h = nnb1[k] + a0 * nnW1[k * 4 + 0] + a1 * nnW1[k * 4 + 1]
                      + a2 * nnW1[k * 4 + 2] + a3 * nnW1[k * 4 + 3];
    h32[e * 32 + k] = fmaxf(h, 0.f);
    if (k == 0) {
        int bi = 0; float bv = a0;
        if (a1 > bv) { bv = a1; bi = 1; }
        if (a2 > bv) { bv = a2; bi = 2; }
        if (a3 > bv) { bv = a3; bi = 3; }
        bond[e] = bi;
    }
}

// ---------------------------------------------------------------- weight pre-transpose: WT[i][go] = W[go][i]
__global__ __launch_bounds__(256) void k_wT(const float* __restrict__ Wih,
                                            const float* __restrict__ Whh,
                                            float* __restrict__ WihT,
                                            float* __restrict__ WhhT) {
    int tid = blockIdx.x * 256 + threadIdx.x;   // 12288 total
    int i = tid / 192, go = tid % 192;
    WihT[tid] = Wih[go * 64 + i];
    WhhT[tid] = Whh[go * 64 + i];
}

// ---------------------------------------------------------------- M[b] = V[b] @ U[b]   (4 x 64x64)
// one block per (bond, output-row); 4 r-chunks of 128, LDS reduce.
__global__ __launch_bounds__(256) void k_M(const float* __restrict__ U,
                                           const float* __restrict__ V,
                                           float* __restrict__ M) {
    int b = blockIdx.x, d = blockIdx.y;
    int tid = threadIdx.x, chunk = tid >> 6, dp = tid & 63;
    const float* Vp = V + ((size_t)b * DIM + d) * RANK;
    const float* Up = U + (size_t)b * RANK * DIM;
    float acc = 0.f;
    for (int r = chunk * 128; r < chunk * 128 + 128; ++r)
        acc += Vp[r] * Up[(size_t)r * DIM + dp];     // Vp: lane-broadcast, Up: coalesced
    __shared__ float red[4][64];
    red[chunk][dp] = acc;
    __syncthreads();
    if (chunk == 0)
        M[((size_t)b * DIM + d) * DIM + dp] =
            red[0][dp] + red[1][dp] + red[2][dp] + red[3][dp];
}

// ---------------------------------------------------------------- A[n][o*32+k] = sum_i s[n][i]*W2[i*2048 + o*32 + k]
// plain tiled fp32 GEMM: [8192,64] @ [64,2048]
__global__ __launch_bounds__(256) void k_gemm_A(const float* __restrict__ s,
                                                const float* __restrict__ W2,
                                                float* __restrict__ A) {
    __shared__ float St[64][65];
    __shared__ float Bt[64][65];
    int n0 = blockIdx.x * 64;
    int j0 = blockIdx.y * 64;
    int tid = threadIdx.x;
    for (int idx = tid; idx < 4096; idx += 256) {
        int r = idx >> 6, i = idx & 63;
        St[r][i] = s[(size_t)(n0 + r) * DIM + i];
    }
    for (int idx = tid; idx < 4096; idx += 256) {
        int i = idx >> 6, j = idx & 63;
        Bt[i][j] = W2[(size_t)i * 2048 + j0 + j];
    }
    __syncthreads();
    int tx = tid & 15, ty = tid >> 4;
    float acc[4][4] = {};
    for (int i = 0; i < 64; ++i) {
        float bv[4];
#pragma unroll
        for (int q = 0; q < 4; ++q) bv[q] = Bt[i][tx * 4 + q];
#pragma unroll
        for (int a = 0; a < 4; ++a) {
            float sa = St[ty * 4 + a][i];
#pragma unroll
            for (int q = 0; q < 4; ++q) acc[a][q] += sa * bv[q];
        }
    }
    for (int a = 0; a < 4; ++a)
        for (int q = 0; q < 4; ++q)
            A[(size_t)(n0 + ty * 4 + a) * 2048 + j0 + tx * 4 + q] = acc[a][q];
}

// ---------------------------------------------------------------- c[n][o] = sum_i s[n][i]*b2[i*64+o]
__global__ __launch_bounds__(256) void k_c(const float* __restrict__ s,
                                           const float* __restrict__ b2,
                                           float* __restrict__ c) {
    __shared__ float ss[4][64];
    int tid = threadIdx.x, w = tid >> 6, lane = tid & 63;
    int node = blockIdx.x * 4 + w;
    ss[w][lane] = s[(size_t)node * DIM + lane];
    __syncthreads();
    float acc = 0.f;
    for (int i = 0; i < 64; ++i) acc += ss[w][i] * b2[i * 64 + lane];
    c[(size_t)node * DIM + lane] = acc;
}

// ---------------------------------------------------------------- edge message + scatter (A path)
__global__ __launch_bounds__(256) void k_edge(const int* __restrict__ ei,
                                              const float* __restrict__ h32,
                                              const float* __restrict__ A,
                                              const float* __restrict__ c,
                                              float* __restrict__ agg) {
    __shared__ float sh[4][32];
    int tid = threadIdx.x, w = tid >> 6, lane = tid & 63;
    int e = blockIdx.x * 4 + w;
    int src = ei[e], dst = ei[NE + e];
    if (lane < 32) sh[w][lane] = h32[(size_t)e * 32 + lane];
    __syncthreads();
    float acc = c[(size_t)src * DIM + lane];
    const float4* Ap = reinterpret_cast<const float4*>(A + (size_t)src * 2048 + lane * 32);
#pragma unroll
    for (int k8 = 0; k8 < 8; ++k8) {
        float4 a = Ap[k8];
        acc += sh[w][k8 * 4 + 0] * a.x + sh[w][k8 * 4 + 1] * a.y
             + sh[w][k8 * 4 + 2] * a.z + sh[w][k8 * 4 + 3] * a.w;
    }
    atomicAdd(&agg[(size_t)dst * DIM + lane], acc);
}

// ---------------------------------------------------------------- fallback edge message (no A buffer)
__global__ __launch_bounds__(256) void k_edge_direct(const int* __restrict__ ei,
                                                     const float* __restrict__ h32,
                                                     const float* __restrict__ s,
                                                     const float* __restrict__ W2,
                                                     const float* __restrict__ b2,
                                                     float* __restrict__ agg) {
    __shared__ float sh[4][32];
    __shared__ float ss[4][64];
    int tid = threadIdx.x, w = tid >> 6, lane = tid & 63;
    int e = blockIdx.x * 4 + w;
    int src = ei[e], dst = ei[NE + e];
    if (lane < 32) sh[w][lane] = h32[(size_t)e * 32 + lane];
    ss[w][lane] = s[(size_t)src * DIM + lane];
    __syncthreads();
    float acc = 0.f;
    for (int i = 0; i < 64; ++i) {
        const float4* Wp = reinterpret_cast<const float4*>(W2 + (size_t)i * 2048 + lane * 32);
        float mi = b2[i * 64 + lane];
#pragma unroll
        for (int k8 = 0; k8 < 8; ++k8) {
            float4 ww = Wp[k8];
            mi += sh[w][k8 * 4 + 0] * ww.x + sh[w][k8 * 4 + 1] * ww.y
                + sh[w][k8 * 4 + 2] * ww.z + sh[w][k8 * 4 + 3] * ww.w;
        }
        acc += ss[w][i] * mi;
    }
    atomicAdd(&agg[(size_t)dst * DIM + lane], acc);
}

// ---------------------------------------------------------------- node update: NNConv combine + GRU cell
// 16 nodes/block; each thread handles one output lane for 4 nodes ->
// every (coalesced) weight load feeds 4 FMAs; 24 independent acc chains.
__global__ __launch_bounds__(256) void k_update(float* __restrict__ s,
                                                const float* __restrict__ agg,
                                                const float* __restrict__ inv_deg,
                                                const float* __restrict__ root,
                                                const float* __restrict__ conv_b,
                                                const float* __restrict__ WihT,
                                                const float* __restrict__ WhhT,
                                                const float* __restrict__ bih,
                                                const float* __restrict__ bhh) {
    __shared__ float sm_s[16][64];
    __shared__ float sm_m[16][64];
    int tid = threadIdx.x, w = tid >> 6, lane = tid & 63;
    int n0 = blockIdx.x * 16;
#pragma unroll
    for (int q = 0; q < 4; ++q) {
        int ln = w + q * 4;
        sm_s[ln][lane] = s[(size_t)(n0 + ln) * DIM + lane];
    }
    __syncthreads();
    // m = relu(h @ root + agg/deg + conv_b)
    float mval[4];
#pragma unroll
    for (int q = 0; q < 4; ++q) {
        int ln = w + q * 4, node = n0 + ln;
        mval[q] = agg[(size_t)node * DIM + lane] * inv_deg[node] + conv_b[lane];
    }
    for (int i = 0; i < 64; ++i) {
        float rv = root[i * 64 + lane];                 // coalesced
#pragma unroll
        for (int q = 0; q < 4; ++q) mval[q] += sm_s[w + q * 4][i] * rv;  // LDS broadcast
    }
#pragma unroll
    for (int q = 0; q < 4; ++q) sm_m[w + q * 4][lane] = fmaxf(mval[q], 0.f);
    __syncthreads();
    // GRU gates
    float gr[4] = {}, gz[4] = {}, gn[4] = {}, hr[4] = {}, hz[4] = {}, hn[4] = {};
    for (int i = 0; i < 64; ++i) {
        float w0 = WihT[i * 192 + lane];
        float w1 = WihT[i * 192 + 64 + lane];
        float w2 = WihT[i * 192 + 128 + lane];
        float v0 = WhhT[i * 192 + lane];
        float v1 = WhhT[i * 192 + 64 + lane];
        float v2 = WhhT[i * 192 + 128 + lane];
#pragma unroll
        for (int q = 0; q < 4; ++q) {
            int ln = w + q * 4;
            float mi = sm_m[ln][i], hi = sm_s[ln][i];   // LDS broadcast
            gr[q] += mi * w0; gz[q] += mi * w1; gn[q] += mi * w2;
            hr[q] += hi * v0; hz[q] += hi * v1; hn[q] += hi * v2;
        }
    }
    float bi0 = bih[lane], bi1 = bih[64 + lane], bi2 = bih[128 + lane];
    float bh0 = bhh[lane], bh1 = bhh[64 + lane], bh2 = bhh[128 + lane];
#pragma unroll
    for (int q = 0; q < 4; ++q) {
        int ln = w + q * 4, node = n0 + ln;
        float r = 1.f / (1.f + expf(-(gr[q] + bi0 + hr[q] + bh0)));
        float z = 1.f / (1.f + expf(-(gz[q] + bi1 + hz[q] + bh1)));
        float nv = tanhf(gn[q] + bi2 + r * (hn[q] + bh2));
        float hv = sm_s[ln][lane];
        s[(size_t)node * DIM + lane] = (1.f - z) * nv + z * hv;
    }
}

// ---------------------------------------------------------------- out_edges + out_combine
__global__ __launch_bounds__(256) void k_edges_out(const float* __restrict__ s,
                                                   const float* __restrict__ x,
                                                   const float* __restrict__ W1l,
                                                   const float* __restrict__ b1l,
                                                   const float* __restrict__ WUp,
                                                   const float* __restrict__ bUp,
                                                   float* __restrict__ oe,
                                                   float* __restrict__ oc) {
    __shared__ float sm_s[4][64];
    __shared__ float sm_oe[4][4];
    int tid = threadIdx.x, w = tid >> 6, lane = tid & 63;
    int node = blockIdx.x * 4 + w;
    float sv = s[(size_t)node * DIM + lane];
    sm_s[w][lane] = sv;
    __syncthreads();
    if (lane < 4) {
        float acc = b1l[lane];
        for (int i = 0; i < 64; ++i) acc += sm_s[w][i] * W1l[lane * 64 + i];
        acc = fmaxf(acc, 0.f);
        sm_oe[w][lane] = acc;
        oe[(size_t)node * 4 + lane] = acc;
    }
    __syncthreads();
    float ocv;
    if (x[(size_t)node * FD] == 2.0f) {
        ocv = bUp[lane];
#pragma unroll
        for (int t = 0; t < 4; ++t) ocv += sm_oe[w][t] * WUp[lane * 4 + t];
    } else {
        ocv = sv;
    }
    oc[(size_t)node * DIM + lane] = ocv;
}

// ---------------------------------------------------------------- FGNet edge: me = oc[src] @ M[bond], scatter
__global__ __launch_bounds__(256) void k_fgedge(const int* __restrict__ ei,
                                                const int* __restrict__ bond,
                                                const float* __restrict__ oc,
                                                const float* __restrict__ M,
                                                float* __restrict__ fg_agg) {
    __shared__ float so[4][64];
    int tid = threadIdx.x, w = tid >> 6, lane = tid & 63;
    int e = blockIdx.x * 4 + w;
    int src = ei[e], dst = ei[NE + e];
    int b = bond[e];
    so[w][lane] = oc[(size_t)src * DIM + lane];
    __syncthreads();
    float acc = 0.f;
    const float* Mp = M + b * DIM * DIM;
    for (int d = 0; d < 64; ++d) acc += so[w][d] * Mp[d * 64 + lane];
    atomicAdd(&fg_agg[(size_t)dst * DIM + lane], acc);
}

// ---------------------------------------------------------------- final: msg_f -> msg_to_edge -> out_edges -> log_softmax
__global__ __launch_bounds__(256) void k_final(const float* __restrict__ fg_agg,
                                               const float* __restrict__ inv_deg,
                                               const float* __restrict__ oe,
                                               const float* __restrict__ WDown,
                                               const float* __restrict__ bDown,
                                               const float* __restrict__ weight_e,
                                               const float* __restrict__ linWe,
                                               const float* __restrict__ linbe,
                                               float* __restrict__ out) {
    int tid = threadIdx.x, w = tid >> 6, lane = tid & 63;
    int node = blockIdx.x * 4 + w;
    float mf = fmaxf(fg_agg[(size_t)node * DIM + lane] * inv_deg[node], 0.f);
    float mte[4];
#pragma unroll
    for (int t = 0; t < 4; ++t) {
        float p = mf * WDown[t * 64 + lane];
#pragma unroll
        for (int off = 32; off; off >>= 1) p += __shfl_xor(p, off);
        mte[t] = p + bDown[t];
    }
    float val[4];
    float mx = -1e30f;
#pragma unroll
    for (int t = 0; t < 4; ++t) {
        float acc = linbe[t];
#pragma unroll
        for (int t2 = 0; t2 < 4; ++t2) acc += weight_e[t2] * mte[t2] * linWe[t * 4 + t2];
        val[t] = oe[(size_t)node * 4 + t] + fmaxf(acc, 0.f);
        mx = fmaxf(mx, val[t]);
    }
    float lse = 0.f;
#pragma unroll
    for (int t = 0; t < 4; ++t) lse += expf(val[t] - mx);
    lse = logf(lse);
    if (lane < 4) out[(size_t)node * 4 + lane] = val[lane] - mx - lse;
}

// ================================================================ host
extern "C" void kernel_launch(void* const* d_in, const int* in_sizes, int n_in,
                              void* d_out, int out_size, void* d_ws, size_t ws_size,
                              hipStream_t stream) {
    const float* x       = (const float*)d_in[0];
    const int*   ei      = (const int*)  d_in[1];
    const float* ea      = (const float*)d_in[2];
    const float* W0      = (const float*)d_in[3];
    const float* b0      = (const float*)d_in[4];
    const float* nnW1    = (const float*)d_in[5];
    const float* nnb1    = (const float*)d_in[6];
    const float* nnW2    = (const float*)d_in[7];
    const float* nnb2    = (const float*)d_in[8];
    const float* root    = (const float*)d_in[9];
    const float* conv_b  = (const float*)d_in[10];
    const float* Wih     = (const float*)d_in[11];
    const float* Whh     = (const float*)d_in[12];
    const float* bih     = (const float*)d_in[13];
    const float* bhh     = (const float*)d_in[14];
    const float* W1l     = (const float*)d_in[15];
    const float* b1l     = (const float*)d_in[16];
    const float* WUp     = (const float*)d_in[17];
    const float* bUp     = (const float*)d_in[18];
    const float* WDown   = (const float*)d_in[19];
    const float* bDown   = (const float*)d_in[20];
    const float* U       = (const float*)d_in[21];
    const float* V       = (const float*)d_in[22];
    // d_in[23..25] weight/linW/linb: dead code (node-'out' branch never reaches output)
    const float* weight_e= (const float*)d_in[26];
    const float* linWe   = (const float*)d_in[27];
    const float* linbe   = (const float*)d_in[28];
    float* out = (float*)d_out;

    char* ws = (char*)d_ws;
    size_t off = 0;
    auto alloc = [&](size_t bytes) { size_t o = off; off = (off + bytes + 255) & ~(size_t)255; return o; };
    float* s      = (float*)(ws + alloc((size_t)NN * DIM * 4));
    float* agg    = (float*)(ws + alloc((size_t)NN * DIM * 4));
    float* h32    = (float*)(ws + alloc((size_t)NE * 32 * 4));
    int*   bond   = (int*)  (ws + alloc((size_t)NE * 4));
    float* deg    = (float*)(ws + alloc((size_t)NN * 4));
    float* oe     = (float*)(ws + alloc((size_t)NN * 4 * 4));
    float* oc     = (float*)(ws + alloc((size_t)NN * DIM * 4));
    float* fg_agg = (float*)(ws + alloc((size_t)NN * DIM * 4));
    float* Mbuf   = (float*)(ws + alloc((size_t)BT * DIM * DIM * 4));
    float* WihT   = (float*)(ws + alloc((size_t)64 * 192 * 4));
    float* WhhT   = (float*)(ws + alloc((size_t)64 * 192 * 4));
    float* cbuf   = (float*)(ws + alloc((size_t)NN * DIM * 4));
    float* Abuf   = (float*)(ws + alloc((size_t)NN * 2048 * 4));
    bool useA = ws_size >= off;
    (void)n_in; (void)in_sizes; (void)out_size;

    k_init<<<NN * DIM / 256, 256, 0, stream>>>(x, W0, b0, s);
    hipMemsetAsync(deg, 0, (size_t)NN * 4, stream);
    k_deg<<<NE / 256, 256, 0, stream>>>(ei, deg);
    k_h32bond<<<NE / 8, 256, 0, stream>>>(ea, nnW1, nnb1, h32, bond);
    k_invdeg<<<NN / 256, 256, 0, stream>>>(deg);   // deg now holds 1/clip(deg,1)
    k_wT<<<48, 256, 0, stream>>>(Wih, Whh, WihT, WhhT);
    k_M<<<dim3(BT, DIM), 256, 0, stream>>>(U, V, Mbuf);

    for (int it = 0; it < 3; ++it) {
        hipMemsetAsync(agg, 0, (size_t)NN * DIM * 4, stream);
        if (useA) {
            k_gemm_A<<<dim3(NN / 64, 2048 / 64), 256, 0, stream>>>(s, nnW2, Abuf);
            k_c<<<NN / 4, 256, 0, stream>>>(s, nnb2, cbuf);
            k_edge<<<NE / 4, 256, 0, stream>>>(ei, h32, Abuf, cbuf, agg);
        } else {
            k_edge_direct<<<NE / 4, 256, 0, stream>>>(ei, h32, s, nnW2, nnb2, agg);
        }
        k_update<<<NN / 16, 256, 0, stream>>>(s, agg, deg, root, conv_b,
                                              WihT, WhhT, bih, bhh);
    }

    k_edges_out<<<NN / 4, 256, 0, stream>>>(s, x, W1l, b1l, WUp, bUp, oe, oc);
    hipMemsetAsync(fg_agg, 0, (size_t)NN * DIM * 4, stream);
    k_fgedge<<<NE / 4, 256, 0, stream>>>(ei, bond, oc, Mbuf, fg_agg);
    k_final<<<NN / 4, 256, 0, stream>>>(fg_agg, deg, oe, WDown, bDown, weight_e, linWe, linbe, out);
}

// Round 3
// 293.172 us; speedup vs baseline: 3.3488x; 1.4308x over previous
//
#include <hip/hip_runtime.h>
#include <hip/hip_bf16.h>

#define NN 8192      // nodes
#define NE 32768     // edges
#define FD 16        // features
#define DIM 64
#define BT 4
#define RANK 512

// bf16 helpers: pack (RNE) and unpack from packed uints
__device__ inline unsigned short f2bf(float f) {
    union { float f; unsigned u; } c; c.f = f;
    return (unsigned short)((c.u + 0x7fffu + ((c.u >> 16) & 1u)) >> 16);
}
__device__ inline float bfl(unsigned u) {   // low ushort -> float
    union { unsigned u; float f; } c; c.u = u << 16; return c.f;
}
__device__ inline float bfh(unsigned u) {   // high ushort -> float
    union { unsigned u; float f; } c; c.u = u & 0xffff0000u; return c.f;
}

// ---------------------------------------------------------------- init: s = relu(x @ W0.T + b0)
__global__ __launch_bounds__(256) void k_init(const float* __restrict__ x,
                                              const float* __restrict__ W0,
                                              const float* __restrict__ b0,
                                              float* __restrict__ s) {
    int gid = blockIdx.x * 256 + threadIdx.x;       // gid = n*64 + d
    int n = gid >> 6, d = gid & 63;
    float acc = b0[d];
    const float* xr = x + n * FD;
    const float* wr = W0 + d * FD;
#pragma unroll
    for (int i = 0; i < FD; ++i) acc += xr[i] * wr[i];
    s[gid] = fmaxf(acc, 0.f);
}

// ---------------------------------------------------------------- degree count
__global__ __launch_bounds__(256) void k_deg(const int* __restrict__ ei, float* __restrict__ deg) {
    int e = blockIdx.x * 256 + threadIdx.x;
    atomicAdd(&deg[ei[NE + e]], 1.0f);
}

__global__ __launch_bounds__(256) void k_invdeg(float* __restrict__ deg) {
    int n = blockIdx.x * 256 + threadIdx.x;
    deg[n] = 1.0f / fmaxf(deg[n], 1.0f);
}

// ---------------------------------------------------------------- per-edge hidden (E,32) + bond argmax
__global__ __launch_bounds__(256) void k_h32bond(const float* __restrict__ ea,
                                                 const float* __restrict__ nnW1,
                                                 const float* __restrict__ nnb1,
                                                 float* __restrict__ h32,
                                                 int* __restrict__ bond) {
    int tid = threadIdx.x;
    int e = blockIdx.x * 8 + (tid >> 5);
    int k = tid & 31;
    float a0 = ea[e * 4 + 0], a1 = ea[e * 4 + 1], a2 = ea[e * 4 + 2], a3 = ea[e * 4 + 3];
    float h = nnb1[k] + a0 * nnW1[k * 4 + 0] + a1 * nnW1[k * 4 + 1]
                      + a2 * nnW1[k * 4 + 2] + a3 * nnW1[k * 4 + 3];
    h32[e * 32 + k] = fmaxf(h, 0.f);
    if (k == 0) {
        int bi = 0; float bv = a0;
        if (a1 > bv) { bv = a1; bi = 1; }
        if (a2 > bv) { bv = a2; bi = 2; }
        if (a3 > bv) { bv = a3; bi = 3; }
        bond[e] = bi;
    }
}

// ---------------------------------------------------------------- weight pre-transpose: WT[i][go] = W[go][i]
__global__ __launch_bounds__(256) void k_wT(const float* __restrict__ Wih,
                                            const float* __restrict__ Whh,
                                            float* __restrict__ WihT,
                                            float* __restrict__ WhhT) {
    int tid = blockIdx.x * 256 + threadIdx.x;   // 12288 total
    int i = tid / 192, go = tid % 192;
    WihT[tid] = Wih[go * 64 + i];
    WhhT[tid] = Whh[go * 64 + i];
}

// ---------------------------------------------------------------- M[b] = V[b] @ U[b]   (4 x 64x64)
__global__ __launch_bounds__(256) void k_M(const float* __restrict__ U,
                                           const float* __restrict__ V,
                                           float* __restrict__ M) {
    int b = blockIdx.x, d = blockIdx.y;
    int tid = threadIdx.x, chunk = tid >> 6, dp = tid & 63;
    const float* Vp = V + ((size_t)b * DIM + d) * RANK;
    const float* Up = U + (size_t)b * RANK * DIM;
    float acc = 0.f;
    for (int r = chunk * 128; r < chunk * 128 + 128; ++r)
        acc += Vp[r] * Up[(size_t)r * DIM + dp];     // Vp: lane-broadcast, Up: coalesced
    __shared__ float red[4][64];
    red[chunk][dp] = acc;
    __syncthreads();
    if (chunk == 0)
        M[((size_t)b * DIM + d) * DIM + dp] =
            red[0][dp] + red[1][dp] + red[2][dp] + red[3][dp];
}

// ---------------------------------------------------------------- A[n][o*32+k] = sum_i s[n][i]*W2[i*2048+o*32+k]
// 128x128 tile, 8x8/thread (split as 2 quads of 4 cols), K split into 2 phases
// of 32 to keep LDS at 33 KB (4 blocks/CU). Output stored as bf16.
__global__ __launch_bounds__(256) void k_gemm_A(const float* __restrict__ s,
                                                const float* __restrict__ W2,
                                                unsigned short* __restrict__ A) {
    __shared__ float St[128][33];   // [m][kk]  (+1 pad: ty-groups land on distinct banks)
    __shared__ float Bt[32][128];   // [kk][j]  (stride-4 lane reads: conflict-free)
    int n0 = blockIdx.x * 128;
    int j0 = blockIdx.y * 128;
    int tid = threadIdx.x;
    int tx = tid & 15, ty = tid >> 4;
    float acc[8][2][4] = {};

    for (int h = 0; h < 2; ++h) {
        if (h) __syncthreads();
        // stage S half: 128 x 32 = 1024 float4
        for (int idx = tid; idx < 1024; idx += 256) {
            int r = idx >> 3, kq = (idx & 7) * 4;
            float4 v = *(const float4*)(s + (size_t)(n0 + r) * DIM + h * 32 + kq);
            St[r][kq] = v.x; St[r][kq + 1] = v.y; St[r][kq + 2] = v.z; St[r][kq + 3] = v.w;
        }
        // stage B half: 32 x 128 = 1024 float4
        for (int idx = tid; idx < 1024; idx += 256) {
            int i = idx >> 5, jq = (idx & 31) * 4;
            float4 v = *(const float4*)(W2 + (size_t)(h * 32 + i) * 2048 + j0 + jq);
            Bt[i][jq] = v.x; Bt[i][jq + 1] = v.y; Bt[i][jq + 2] = v.z; Bt[i][jq + 3] = v.w;
        }
        __syncthreads();
        for (int kk = 0; kk < 32; ++kk) {
            float bv0[4], bv1[4], av[8];
#pragma unroll
            for (int b = 0; b < 4; ++b) bv0[b] = Bt[kk][tx * 4 + b];
#pragma unroll
            for (int b = 0; b < 4; ++b) bv1[b] = Bt[kk][64 + tx * 4 + b];
#pragma unroll
            for (int a = 0; a < 8; ++a) av[a] = St[ty * 8 + a][kk];
#pragma unroll
            for (int a = 0; a < 8; ++a) {
#pragma unroll
                for (int b = 0; b < 4; ++b) acc[a][0][b] += av[a] * bv0[b];
#pragma unroll
                for (int b = 0; b < 4; ++b) acc[a][1][b] += av[a] * bv1[b];
            }
        }
    }
    // write bf16: per row, two quads of 4 bf16 (8B each)
#pragma unroll
    for (int a = 0; a < 8; ++a) {
        size_t row = (size_t)(n0 + ty * 8 + a) * 2048 + j0;
#pragma unroll
        for (int q = 0; q < 2; ++q) {
            union { unsigned short h[4]; uint2 v; } p;
#pragma unroll
            for (int b = 0; b < 4; ++b) p.h[b] = f2bf(acc[a][q][b]);
            *(uint2*)(A + row + q * 64 + tx * 4) = p.v;
        }
    }
}

// ---------------------------------------------------------------- c[n][o] = sum_i s[n][i]*b2[i*64+o]
__global__ __launch_bounds__(256) void k_c(const float* __restrict__ s,
                                           const float* __restrict__ b2,
                                           float* __restrict__ c) {
    __shared__ float ss[4][64];
    int tid = threadIdx.x, w = tid >> 6, lane = tid & 63;
    int node = blockIdx.x * 4 + w;
    ss[w][lane] = s[(size_t)node * DIM + lane];
    __syncthreads();
    float acc = 0.f;
    for (int i = 0; i < 64; ++i) acc += ss[w][i] * b2[i * 64 + lane];
    c[(size_t)node * DIM + lane] = acc;
}

// ---------------------------------------------------------------- edge message + scatter (bf16 A path)
__global__ __launch_bounds__(256) void k_edge(const int* __restrict__ ei,
                                              const float* __restrict__ h32,
                                              const unsigned short* __restrict__ A,
                                              const float* __restrict__ c,
                                              float* __restrict__ agg) {
    __shared__ float sh[4][32];
    int tid = threadIdx.x, w = tid >> 6, o = tid & 63;
    int e = blockIdx.x * 4 + w;
    int src = ei[e], dst = ei[NE + e];
    if (o < 32) sh[w][o] = h32[(size_t)e * 32 + o];
    __syncthreads();
    float acc = c[(size_t)src * DIM + o];
    const uint4* Ap = reinterpret_cast<const uint4*>(A + (size_t)src * 2048 + o * 32);
    const float* hp = sh[w];
#pragma unroll
    for (int q = 0; q < 4; ++q) {
        uint4 v = Ap[q];
        const float* hq = hp + q * 8;
        acc += hq[0] * bfl(v.x) + hq[1] * bfh(v.x)
             + hq[2] * bfl(v.y) + hq[3] * bfh(v.y)
             + hq[4] * bfl(v.z) + hq[5] * bfh(v.z)
             + hq[6] * bfl(v.w) + hq[7] * bfh(v.w);
    }
    atomicAdd(&agg[(size_t)dst * DIM + o], acc);
}

// ---------------------------------------------------------------- fallback edge message (no A buffer)
__global__ __launch_bounds__(256) void k_edge_direct(const int* __restrict__ ei,
                                                     const float* __restrict__ h32,
                                                     const float* __restrict__ s,
                                                     const float* __restrict__ W2,
                                                     const float* __restrict__ b2,
                                                     float* __restrict__ agg) {
    __shared__ float sh[4][32];
    __shared__ float ss[4][64];
    int tid = threadIdx.x, w = tid >> 6, lane = tid & 63;
    int e = blockIdx.x * 4 + w;
    int src = ei[e], dst = ei[NE + e];
    if (lane < 32) sh[w][lane] = h32[(size_t)e * 32 + lane];
    ss[w][lane] = s[(size_t)src * DIM + lane];
    __syncthreads();
    float acc = 0.f;
    for (int i = 0; i < 64; ++i) {
        const float4* Wp = reinterpret_cast<const float4*>(W2 + (size_t)i * 2048 + lane * 32);
        float mi = b2[i * 64 + lane];
#pragma unroll
        for (int k8 = 0; k8 < 8; ++k8) {
            float4 ww = Wp[k8];
            mi += sh[w][k8 * 4 + 0] * ww.x + sh[w][k8 * 4 + 1] * ww.y
                + sh[w][k8 * 4 + 2] * ww.z + sh[w][k8 * 4 + 3] * ww.w;
        }
        acc += ss[w][i] * mi;
    }
    atomicAdd(&agg[(size_t)dst * DIM + lane], acc);
}

// ---------------------------------------------------------------- node update: NNConv combine + GRU cell
__global__ __launch_bounds__(256) void k_update(float* __restrict__ s,
                                                const float* __restrict__ agg,
                                                const float* __restrict__ inv_deg,
                                                const float* __restrict__ root,
                                                const float* __restrict__ conv_b,
                                                const float* __restrict__ WihT,
                                                const float* __restrict__ WhhT,
                                                const float* __restrict__ bih,
                                                const float* __restrict__ bhh) {
    __shared__ float sm_s[16][64];
    __shared__ float sm_m[16][64];
    int tid = threadIdx.x, w = tid >> 6, lane = tid & 63;
    int n0 = blockIdx.x * 16;
#pragma unroll
    for (int q = 0; q < 4; ++q) {
        int ln = w + q * 4;
        sm_s[ln][lane] = s[(size_t)(n0 + ln) * DIM + lane];
    }
    __syncthreads();
    float mval[4];
#pragma unroll
    for (int q = 0; q < 4; ++q) {
        int ln = w + q * 4, node = n0 + ln;
        mval[q] = agg[(size_t)node * DIM + lane] * inv_deg[node] + conv_b[lane];
    }
    for (int i = 0; i < 64; ++i) {
        float rv = root[i * 64 + lane];
#pragma unroll
        for (int q = 0; q < 4; ++q) mval[q] += sm_s[w + q * 4][i] * rv;
    }
#pragma unroll
    for (int q = 0; q < 4; ++q) sm_m[w + q * 4][lane] = fmaxf(mval[q], 0.f);
    __syncthreads();
    float gr[4] = {}, gz[4] = {}, gn[4] = {}, hr[4] = {}, hz[4] = {}, hn[4] = {};
    for (int i = 0; i < 64; ++i) {
        float w0 = WihT[i * 192 + lane];
        float w1 = WihT[i * 192 + 64 + lane];
        float w2 = WihT[i * 192 + 128 + lane];
        float v0 = WhhT[i * 192 + lane];
        float v1 = WhhT[i * 192 + 64 + lane];
        float v2 = WhhT[i * 192 + 128 + lane];
#pragma unroll
        for (int q = 0; q < 4; ++q) {
            int ln = w + q * 4;
            float mi = sm_m[ln][i], hi = sm_s[ln][i];
            gr[q] += mi * w0; gz[q] += mi * w1; gn[q] += mi * w2;
            hr[q] += hi * v0; hz[q] += hi * v1; hn[q] += hi * v2;
        }
    }
    float bi0 = bih[lane], bi1 = bih[64 + lane], bi2 = bih[128 + lane];
    float bh0 = bhh[lane], bh1 = bhh[64 + lane], bh2 = bhh[128 + lane];
#pragma unroll
    for (int q = 0; q < 4; ++q) {
        int ln = w + q * 4, node = n0 + ln;
        float r = 1.f / (1.f + expf(-(gr[q] + bi0 + hr[q] + bh0)));
        float z = 1.f / (1.f + expf(-(gz[q] + bi1 + hz[q] + bh1)));
        float nv = tanhf(gn[q] + bi2 + r * (hn[q] + bh2));
        float hv = sm_s[ln][lane];
        s[(size_t)node * DIM + lane] = (1.f - z) * nv + z * hv;
    }
}

// ---------------------------------------------------------------- out_edges + out_combine
__global__ __launch_bounds__(256) void k_edges_out(const float* __restrict__ s,
                                                   const float* __restrict__ x,
                                                   const float* __restrict__ W1l,
                                                   const float* __restrict__ b1l,
                                                   const float* __restrict__ WUp,
                                                   const float* __restrict__ bUp,
                                                   float* __restrict__ oe,
                                                   float* __restrict__ oc) {
    __shared__ float sm_s[4][64];
    __shared__ float sm_oe[4][4];
    int tid = threadIdx.x, w = tid >> 6, lane = tid & 63;
    int node = blockIdx.x * 4 + w;
    float sv = s[(size_t)node * DIM + lane];
    sm_s[w][lane] = sv;
    __syncthreads();
    if (lane < 4) {
        float acc = b1l[lane];
        for (int i = 0; i < 64; ++i) acc += sm_s[w][i] * W1l[lane * 64 + i];
        acc = fmaxf(acc, 0.f);
        sm_oe[w][lane] = acc;
        oe[(size_t)node * 4 + lane] = acc;
    }
    __syncthreads();
    float ocv;
    if (x[(size_t)node * FD] == 2.0f) {
        ocv = bUp[lane];
#pragma unroll
        for (int t = 0; t < 4; ++t) ocv += sm_oe[w][t] * WUp[lane * 4 + t];
    } else {
        ocv = sv;
    }
    oc[(size_t)node * DIM + lane] = ocv;
}

// ---------------------------------------------------------------- FGNet edge: me = oc[src] @ M[bond], scatter
__global__ __launch_bounds__(256) void k_fgedge(const int* __restrict__ ei,
                                                const int* __restrict__ bond,
                                                const float* __restrict__ oc,
                                                const float* __restrict__ M,
                                                float* __restrict__ fg_agg) {
    __shared__ float so[4][64];
    int tid = threadIdx.x, w = tid >> 6, lane = tid & 63;
    int e = blockIdx.x * 4 + w;
    int src = ei[e], dst = ei[NE + e];
    int b = bond[e];
    so[w][lane] = oc[(size_t)src * DIM + lane];
    __syncthreads();
    float acc = 0.f;
    const float* Mp = M + b * DIM * DIM;
    for (int d = 0; d < 64; ++d) acc += so[w][d] * Mp[d * 64 + lane];
    atomicAdd(&fg_agg[(size_t)dst * DIM + lane], acc);
}

// ---------------------------------------------------------------- final: msg_f -> msg_to_edge -> out_edges -> log_softmax
__global__ __launch_bounds__(256) void k_final(const float* __restrict__ fg_agg,
                                               const float* __restrict__ inv_deg,
                                               const float* __restrict__ oe,
                                               const float* __restrict__ WDown,
                                               const float* __restrict__ bDown,
                                               const float* __restrict__ weight_e,
                                               const float* __restrict__ linWe,
                                               const float* __restrict__ linbe,
                                               float* __restrict__ out) {
    int tid = threadIdx.x, w = tid >> 6, lane = tid & 63;
    int node = blockIdx.x * 4 + w;
    float mf = fmaxf(fg_agg[(size_t)node * DIM + lane] * inv_deg[node], 0.f);
    float mte[4];
#pragma unroll
    for (int t = 0; t < 4; ++t) {
        float p = mf * WDown[t * 64 + lane];
#pragma unroll
        for (int off = 32; off; off >>= 1) p += __shfl_xor(p, off);
        mte[t] = p + bDown[t];
    }
    float val[4];
    float mx = -1e30f;
#pragma unroll
    for (int t = 0; t < 4; ++t) {
        float acc = linbe[t];
#pragma unroll
        for (int t2 = 0; t2 < 4; ++t2) acc += weight_e[t2] * mte[t2] * linWe[t * 4 + t2];
        val[t] = oe[(size_t)node * 4 + t] + fmaxf(acc, 0.f);
        mx = fmaxf(mx, val[t]);
    }
    float lse = 0.f;
#pragma unroll
    for (int t = 0; t < 4; ++t) lse += expf(val[t] - mx);
    lse = logf(lse);
    if (lane < 4) out[(size_t)node * 4 + lane] = val[lane] - mx - lse;
}

// ================================================================ host
extern "C" void kernel_launch(void* const* d_in, const int* in_sizes, int n_in,
                              void* d_out, int out_size, void* d_ws, size_t ws_size,
                              hipStream_t stream) {
    const float* x       = (const float*)d_in[0];
    const int*   ei      = (const int*)  d_in[1];
    const float* ea      = (const float*)d_in[2];
    const float* W0      = (const float*)d_in[3];
    const float* b0      = (const float*)d_in[4];
    const float* nnW1    = (const float*)d_in[5];
    const float* nnb1    = (const float*)d_in[6];
    const float* nnW2    = (const float*)d_in[7];
    const float* nnb2    = (const float*)d_in[8];
    const float* root    = (const float*)d_in[9];
    const float* conv_b  = (const float*)d_in[10];
    const float* Wih     = (const float*)d_in[11];
    const float* Whh     = (const float*)d_in[12];
    const float* bih     = (const float*)d_in[13];
    const float* bhh     = (const float*)d_in[14];
    const float* W1l     = (const float*)d_in[15];
    const float* b1l     = (const float*)d_in[16];
    const float* WUp     = (const float*)d_in[17];
    const float* bUp     = (const float*)d_in[18];
    const float* WDown   = (const float*)d_in[19];
    const float* bDown   = (const float*)d_in[20];
    const float* U       = (const float*)d_in[21];
    const float* V       = (const float*)d_in[22];
    // d_in[23..25] weight/linW/linb: dead code (node-'out' branch never reaches output)
    const float* weight_e= (const float*)d_in[26];
    const float* linWe   = (const float*)d_in[27];
    const float* linbe   = (const float*)d_in[28];
    float* out = (float*)d_out;

    char* ws = (char*)d_ws;
    size_t off = 0;
    auto alloc = [&](size_t bytes) { size_t o = off; off = (off + bytes + 255) & ~(size_t)255; return o; };
    float* s      = (float*)(ws + alloc((size_t)NN * DIM * 4));
    float* agg    = (float*)(ws + alloc((size_t)NN * DIM * 4));
    float* h32    = (float*)(ws + alloc((size_t)NE * 32 * 4));
    int*   bond   = (int*)  (ws + alloc((size_t)NE * 4));
    float* deg    = (float*)(ws + alloc((size_t)NN * 4));
    float* oe     = (float*)(ws + alloc((size_t)NN * 4 * 4));
    float* oc     = (float*)(ws + alloc((size_t)NN * DIM * 4));
    float* fg_agg = (float*)(ws + alloc((size_t)NN * DIM * 4));
    float* Mbuf   = (float*)(ws + alloc((size_t)BT * DIM * DIM * 4));
    float* WihT   = (float*)(ws + alloc((size_t)64 * 192 * 4));
    float* WhhT   = (float*)(ws + alloc((size_t)64 * 192 * 4));
    float* cbuf   = (float*)(ws + alloc((size_t)NN * DIM * 4));
    unsigned short* Abuf = (unsigned short*)(ws + alloc((size_t)NN * 2048 * 2));
    bool useA = ws_size >= off;
    (void)n_in; (void)in_sizes; (void)out_size;

    k_init<<<NN * DIM / 256, 256, 0, stream>>>(x, W0, b0, s);
    hipMemsetAsync(deg, 0, (size_t)NN * 4, stream);
    k_deg<<<NE / 256, 256, 0, stream>>>(ei, deg);
    k_h32bond<<<NE / 8, 256, 0, stream>>>(ea, nnW1, nnb1, h32, bond);
    k_invdeg<<<NN / 256, 256, 0, stream>>>(deg);   // deg now holds 1/clip(deg,1)
    k_wT<<<48, 256, 0, stream>>>(Wih, Whh, WihT, WhhT);
    k_M<<<dim3(BT, DIM), 256, 0, stream>>>(U, V, Mbuf);

    for (int it = 0; it < 3; ++it) {
        hipMemsetAsync(agg, 0, (size_t)NN * DIM * 4, stream);
        if (useA) {
            k_gemm_A<<<dim3(NN / 128, 2048 / 128), 256, 0, stream>>>(s, nnW2, Abuf);
            k_c<<<NN / 4, 256, 0, stream>>>(s, nnb2, cbuf);
            k_edge<<<NE / 4, 256, 0, stream>>>(ei, h32, Abuf, cbuf, agg);
        } else {
            k_edge_direct<<<NE / 4, 256, 0, stream>>>(ei, h32, s, nnW2, nnb2, agg);
        }
        k_update<<<NN / 16, 256, 0, stream>>>(s, agg, deg, root, conv_b,
                                              WihT, WhhT, bih, bhh);
    }

    k_edges_out<<<NN / 4, 256, 0, stream>>>(s, x, W1l, b1l, WUp, bUp, oe, oc);
    hipMemsetAsync(fg_agg, 0, (size_t)NN * DIM * 4, stream);
    k_fgedge<<<NE / 4, 256, 0, stream>>>(ei, bond, oc, Mbuf, fg_agg);
    k_final<<<NN / 4, 256, 0, stream>>>(fg_agg, deg, oe, WDown, bDown, weight_e, linWe, linbe, out);
}